// Round 10
// baseline (256.248 us; speedup 1.0000x reference)
//
#include <hip/hip_runtime.h>
#include <hip/hip_bf16.h>
#include <math.h>

// Problem constants
constexpr int kB  = 2;
constexpr int kT  = 2048;
constexpr int kD  = 1024;
constexpr int kH  = 16;
constexpr int kDH = 64;     // per-head dim
constexpr int kC  = 128;    // compressed dim
constexpr int kM  = kB * kT;   // 4096 rows
constexpr int kBH = kB * kH;   // 32

#define LOG10000_OVER_32 0.28782313662425575f
#define QSCALE 0.1803368801111773f   // (1/8) * log2(e): softmax via exp2

typedef unsigned short ushort_t;
using short8 = __attribute__((ext_vector_type(8))) short;
using f32x4  = __attribute__((ext_vector_type(4))) float;

__device__ inline ushort_t f2bf(float f) {
    __hip_bfloat16 h = __float2bfloat16(f);
    return *reinterpret_cast<ushort_t*>(&h);
}

// 8 consecutive f32 -> short8 of bf16
__device__ inline short8 cvt8(const float* p) {
    float4 f0 = *reinterpret_cast<const float4*>(p);
    float4 f1 = *reinterpret_cast<const float4*>(p + 4);
    short8 v;
    v[0] = (short)f2bf(f0.x); v[1] = (short)f2bf(f0.y);
    v[2] = (short)f2bf(f0.z); v[3] = (short)f2bf(f0.w);
    v[4] = (short)f2bf(f1.x); v[5] = (short)f2bf(f1.y);
    v[6] = (short)f2bf(f1.z); v[7] = (short)f2bf(f1.w);
    return v;
}

// ---------------------------------------------------------------------------
// z=0..4: transpose-cast weight f32 (R,C) -> bf16 (C,R), 32x32 LDS tiles.
// z=5: build RoPE cos/sin table tab[t][i] (t<2048, i<32).
// ---------------------------------------------------------------------------
__global__ __launch_bounds__(256)
void wtrans(const float* __restrict__ w_dk, const float* __restrict__ w_dv,
            const float* __restrict__ w_uk, const float* __restrict__ w_uv,
            const float* __restrict__ w_o,
            ushort_t* __restrict__ dkT, ushort_t* __restrict__ dvT,
            ushort_t* __restrict__ ukT, ushort_t* __restrict__ uvT,
            ushort_t* __restrict__ oT, float2* __restrict__ tab) {
    if (blockIdx.z == 5) {
        int flat = blockIdx.y * 32 + blockIdx.x;
        if (flat >= kT / 8) return;
        int t = flat * 8 + (threadIdx.x >> 5);
        int i = threadIdx.x & 31;
        float inv_freq = expf(-(float)i * LOG10000_OVER_32);
        float s, c;
        sincosf((float)t * inv_freq, &s, &c);
        tab[t * 32 + i] = make_float2(c, s);
        return;
    }
    const float* src; ushort_t* dst; int R, C;
    switch (blockIdx.z) {
        case 0: src = w_dk; dst = dkT; R = kD; C = kC; break;
        case 1: src = w_dv; dst = dvT; R = kD; C = kC; break;
        case 2: src = w_uk; dst = ukT; R = kC; C = kD; break;
        case 3: src = w_uv; dst = uvT; R = kC; C = kD; break;
        default: src = w_o; dst = oT;  R = kD; C = kD; break;
    }
    int c0 = blockIdx.x * 32, r0 = blockIdx.y * 32;
    if (c0 >= C || r0 >= R) return;

    __shared__ float Tl[32][33];
    int tx = threadIdx.x & 31, ty = threadIdx.x >> 5;
#pragma unroll
    for (int i = 0; i < 4; ++i)
        Tl[ty + 8 * i][tx] = src[(size_t)(r0 + ty + 8 * i) * C + c0 + tx];
    __syncthreads();
#pragma unroll
    for (int i = 0; i < 4; ++i)
        dst[(size_t)(c0 + ty + 8 * i) * R + r0 + tx] = f2bf(Tl[tx][ty + 8 * i]);
}

// ---------------------------------------------------------------------------
// bf16 MFMA GEMM, 128x128 tile, BK=32, 4 waves (2x2), wave = 64x64 out.
// MODE: 2 = bf16 transposed V (B,H,DH,T); 4 = bf16 split + fused RoPE (k).
// Used for the up-projection only.
// ---------------------------------------------------------------------------
template<int MODE0, int MODE1>
__global__ __launch_bounds__(256)
void gemm_mfma(const ushort_t* __restrict__ A0_, const ushort_t* __restrict__ A1_,
               const ushort_t* __restrict__ Wt0, const float* __restrict__ bias0, void* __restrict__ C0,
               const ushort_t* __restrict__ Wt1, const float* __restrict__ bias1, void* __restrict__ C1,
               const float2* __restrict__ tab, int M, int N, int K) {
    constexpr int LDT = 40;
    __shared__ __align__(16) ushort_t As[128 * LDT];
    __shared__ __align__(16) ushort_t Bs[128 * LDT];

    const ushort_t* A    = blockIdx.z ? A1_ : A0_;
    const ushort_t* Wt   = blockIdx.z ? Wt1 : Wt0;
    const float*    bias = blockIdx.z ? bias1 : bias0;
    void*           Cc   = blockIdx.z ? C1 : C0;
    const int       mode = blockIdx.z ? MODE1 : MODE0;

    const int tid  = threadIdx.x;
    const int wave = tid >> 6, lane = tid & 63;
    const int g = lane >> 4, cl = lane & 15;
    const int m0 = blockIdx.y * 128, n0 = blockIdx.x * 128;
    const int wm = (wave >> 1) * 64, wn = (wave & 1) * 64;

    const int ar = tid >> 1;
    const int ac = (tid & 1) * 16;

    f32x4 acc[4][4] = {};

    for (int k0 = 0; k0 < K; k0 += 32) {
        {
            const ushort_t* Ab = A + (size_t)(m0 + ar) * K + k0 + ac;
            *reinterpret_cast<short8*>(&As[ar * LDT + ac])     = *reinterpret_cast<const short8*>(Ab);
            *reinterpret_cast<short8*>(&As[ar * LDT + ac + 8]) = *reinterpret_cast<const short8*>(Ab + 8);
            const ushort_t* Wb = Wt + (size_t)(n0 + ar) * K + k0 + ac;
            *reinterpret_cast<short8*>(&Bs[ar * LDT + ac])     = *reinterpret_cast<const short8*>(Wb);
            *reinterpret_cast<short8*>(&Bs[ar * LDT + ac + 8]) = *reinterpret_cast<const short8*>(Wb + 8);
        }
        __syncthreads();

        short8 a[4], b[4];
#pragma unroll
        for (int mi = 0; mi < 4; ++mi)
            a[mi] = *reinterpret_cast<const short8*>(&As[(wm + mi * 16 + cl) * LDT + g * 8]);
#pragma unroll
        for (int ni = 0; ni < 4; ++ni)
            b[ni] = *reinterpret_cast<const short8*>(&Bs[(wn + ni * 16 + cl) * LDT + g * 8]);
#pragma unroll
        for (int mi = 0; mi < 4; ++mi)
#pragma unroll
            for (int ni = 0; ni < 4; ++ni)
                acc[mi][ni] = __builtin_amdgcn_mfma_f32_16x16x32_bf16(a[mi], b[ni], acc[mi][ni], 0, 0, 0);
        __syncthreads();
    }

#pragma unroll
    for (int mi = 0; mi < 4; ++mi) {
        if (mode == 4) {
            const int h = (n0 + wn) >> 6;
#pragma unroll
            for (int r = 0; r < 4; ++r) {
                const int m = m0 + wm + mi * 16 + 4 * g + r;
                const int bb = m >> 11, t = m & (kT - 1);
                ushort_t* kp = (ushort_t*)Cc + (((size_t)bb * kH + h) * kT + t) * kDH;
#pragma unroll
                for (int pr = 0; pr < 2; ++pr) {
                    const int i = pr * 16 + cl;
                    float2 cs = tab[t * 32 + i];
                    float v1 = acc[mi][pr][r]     + bias[n0 + wn + pr * 16 + cl];
                    float v2 = acc[mi][pr + 2][r] + bias[n0 + wn + (pr + 2) * 16 + cl];
                    kp[i]      = f2bf(v1 * cs.x - v2 * cs.y);
                    kp[i + 32] = f2bf(v2 * cs.x + v1 * cs.y);
                }
            }
        } else {  // mode 2: bf16 V^T (B,H,DH,T)
#pragma unroll
            for (int ni = 0; ni < 4; ++ni) {
                const int mb = m0 + wm + mi * 16 + 4 * g;
                const int nn = n0 + wn + ni * 16 + cl;
                const float bv = bias[nn];
                const int h = nn >> 6, d = nn & (kDH - 1);
                const int bb = mb >> 11, t0 = mb & (kT - 1);
                uint2 u;
                u.x = (unsigned int)f2bf(acc[mi][ni][0] + bv) | ((unsigned int)f2bf(acc[mi][ni][1] + bv) << 16);
                u.y = (unsigned int)f2bf(acc[mi][ni][2] + bv) | ((unsigned int)f2bf(acc[mi][ni][3] + bv) << 16);
                ushort_t* vt = (ushort_t*)Cc;
                *reinterpret_cast<uint2*>(&vt[(((size_t)bb * kH + h) * kDH + d) * kT + t0]) = u;
            }
        }
    }
}

// ---------------------------------------------------------------------------
// bf16 MFMA GEMM, 128x64 tile, BK=32, 4 waves (2x2), wave = 64x32 out.
// AF32: A is f32 (cast in staging).  MODE: 0 = f32 (M,N); 3 = bf16 (M,N).
// ---------------------------------------------------------------------------
template<bool AF32, int MODE>
__global__ __launch_bounds__(256)
void gemm64(const void* __restrict__ A0_, const void* __restrict__ A1_,
            const ushort_t* __restrict__ Wt0, const float* __restrict__ bias0, void* __restrict__ C0,
            const ushort_t* __restrict__ Wt1, const float* __restrict__ bias1, void* __restrict__ C1,
            int M, int N, int K) {
    constexpr int LDT = 40;
    __shared__ __align__(16) ushort_t As[128 * LDT];
    __shared__ __align__(16) ushort_t Bs[64 * LDT];

    const void*     A    = blockIdx.z ? A1_ : A0_;
    const ushort_t* Wt   = blockIdx.z ? Wt1 : Wt0;
    const float*    bias = blockIdx.z ? bias1 : bias0;
    void*           Cc   = blockIdx.z ? C1 : C0;

    const int tid  = threadIdx.x;
    const int wave = tid >> 6, lane = tid & 63;
    const int g = lane >> 4, cl = lane & 15;
    const int m0 = blockIdx.y * 128, n0 = blockIdx.x * 64;
    const int wm = (wave >> 1) * 64, wn = (wave & 1) * 32;

    const int ar = tid >> 1, ac = (tid & 1) * 16;    // A: 128 rows x 2 chunks
    const int br = tid >> 2, bc = (tid & 3) * 8;     // B: 64 rows x 4 chunks

    f32x4 acc[4][2] = {};

    for (int k0 = 0; k0 < K; k0 += 32) {
        if constexpr (AF32) {
            const float* Af = (const float*)A + (size_t)(m0 + ar) * K + k0 + ac;
            *reinterpret_cast<short8*>(&As[ar * LDT + ac])     = cvt8(Af);
            *reinterpret_cast<short8*>(&As[ar * LDT + ac + 8]) = cvt8(Af + 8);
        } else {
            const ushort_t* Ab = (const ushort_t*)A + (size_t)(m0 + ar) * K + k0 + ac;
            *reinterpret_cast<short8*>(&As[ar * LDT + ac])     = *reinterpret_cast<const short8*>(Ab);
            *reinterpret_cast<short8*>(&As[ar * LDT + ac + 8]) = *reinterpret_cast<const short8*>(Ab + 8);
        }
        *reinterpret_cast<short8*>(&Bs[br * LDT + bc]) =
            *reinterpret_cast<const short8*>(Wt + (size_t)(n0 + br) * K + k0 + bc);
        __syncthreads();

        short8 a[4], b[2];
#pragma unroll
        for (int mi = 0; mi < 4; ++mi)
            a[mi] = *reinterpret_cast<const short8*>(&As[(wm + mi * 16 + cl) * LDT + g * 8]);
#pragma unroll
        for (int ni = 0; ni < 2; ++ni)
            b[ni] = *reinterpret_cast<const short8*>(&Bs[(wn + ni * 16 + cl) * LDT + g * 8]);
#pragma unroll
        for (int mi = 0; mi < 4; ++mi)
#pragma unroll
            for (int ni = 0; ni < 2; ++ni)
                acc[mi][ni] = __builtin_amdgcn_mfma_f32_16x16x32_bf16(a[mi], b[ni], acc[mi][ni], 0, 0, 0);
        __syncthreads();
    }

#pragma unroll
    for (int mi = 0; mi < 4; ++mi)
#pragma unroll
        for (int ni = 0; ni < 2; ++ni) {
            const int mb = m0 + wm + mi * 16 + 4 * g;
            const int nn = n0 + wn + ni * 16 + cl;
            const float bv = bias[nn];
            if constexpr (MODE == 0) {
#pragma unroll
                for (int r = 0; r < 4; ++r)
                    ((float*)Cc)[(size_t)(mb + r) * N + nn] = acc[mi][ni][r] + bv;
            } else {
#pragma unroll
                for (int r = 0; r < 4; ++r)
                    ((ushort_t*)Cc)[(size_t)(mb + r) * N + nn] = f2bf(acc[mi][ni][r] + bv);
            }
        }
}

// ---------------------------------------------------------------------------
// RoPE q (separate kernel — r5 config, the best-measured): x (B,T,D) f32 ->
// q_bf (B,H,T,DH) bf16 scaled by (1/8)*log2e.
// ---------------------------------------------------------------------------
__global__ __launch_bounds__(256)
void rope_split_q(const float* __restrict__ x, const float2* __restrict__ tab,
                  ushort_t* __restrict__ q_bf) {
    int idx = blockIdx.x * 256 + threadIdx.x;
    int i = idx & 31;
    int h = (idx >> 5) & (kH - 1);
    int t = (idx >> 9) & (kT - 1);
    int b = idx >> 20;

    const float* xp = x + ((size_t)(b * kT + t)) * kD + h * kDH;
    float x1 = xp[i];
    float x2 = xp[i + 32];
    float2 cs = tab[t * 32 + i];

    ushort_t* qp = q_bf + (((size_t)(b * kH + h)) * kT + t) * kDH;
    qp[i]      = f2bf((x1 * cs.x - x2 * cs.y) * QSCALE);
    qp[i + 32] = f2bf((x2 * cs.x + x1 * cs.y) * QSCALE);
}

// ---------------------------------------------------------------------------
// MFMA bf16 attention, KEY-SPLIT x2 (no-max softmax is associative over key
// blocks: partial acc and l just add). Grid 2048 = 32qt x 32bh x 2half ->
// 8 blocks/CU (double r5's occupancy). Each block: 1024 keys, 32 iters.
// r5 loop structure (best measured): staged K (XOR-swizzled, r8-verified
// 0-conflict) + V^T (padded LDV=40, r5-verified) + P (LDP=36, r6-verified).
// Writes f32 partial acc + partial l; combine kernel divides.
// ---------------------------------------------------------------------------
__global__ __launch_bounds__(256)
void attn_mfma(const ushort_t* __restrict__ q_bf, const ushort_t* __restrict__ k_bf,
               const ushort_t* __restrict__ vt_bf,
               float* __restrict__ pacc, float* __restrict__ pl) {
    constexpr int LDV = 40;
    constexpr int LDP = 36;
    const int blk  = blockIdx.x;
    const int bh   = (blk & 7) * 4 + ((blk >> 3) & 3);   // XCD-swizzled
    const int half = (blk >> 5) & 1;
    const int qt   = blk >> 6;                           // 0..31
    const int tid  = threadIdx.x;
    const int wave = tid >> 6, lane = tid & 63;
    const int g = lane >> 4, c = lane & 15;
    const int qbase = qt * 64 + wave * 16;

    __shared__ __align__(16) ushort_t Ks[32 * 64];       // XOR-swizzled
    __shared__ __align__(16) ushort_t Vs[64 * LDV];      // padded V^T tile
    __shared__ __align__(16) ushort_t P_lds[4][16 * LDP];
    ushort_t* P = P_lds[wave];

    // Q A-fragments from q_bf (pre-scaled)
    const ushort_t* qp = q_bf + ((size_t)bh * kT + qbase) * kDH;
    short8 qa0 = *reinterpret_cast<const short8*>(qp + (size_t)c * kDH + g * 8);
    short8 qa1 = *reinterpret_cast<const short8*>(qp + (size_t)c * kDH + g * 8 + 32);

    const ushort_t* kb = k_bf + (size_t)bh * kT * kDH;
    const ushort_t* vb = vt_bf + (size_t)bh * kDH * kT;

    const int kr_ = tid >> 3, kc_ = (tid & 7) * 8;            // K tile: 32 x 64
    const int ksw = kr_ * 64 + (kc_ ^ ((kr_ & 7) << 3));      // swizzled store idx
    const int vr_ = tid >> 2, vc_ = (tid & 3) * 8;            // V tile: 64 x 32

    f32x4 acc[4] = {};
    float lsum[4] = {};

    const int kt0 = half * (kT / 2);
    for (int kt = kt0; kt < kt0 + kT / 2; kt += 32) {
        *reinterpret_cast<short8*>(&Ks[ksw]) =
            *reinterpret_cast<const short8*>(&kb[(size_t)(kt + kr_) * kDH + kc_]);
        *reinterpret_cast<short8*>(&Vs[vr_ * LDV + vc_]) =
            *reinterpret_cast<const short8*>(&vb[(size_t)vr_ * kT + kt + vc_]);
        __syncthreads();

        short8 kf[2][2];
#pragma unroll
        for (int kj = 0; kj < 2; ++kj)
#pragma unroll
            for (int f = 0; f < 2; ++f) {
                const int row = kj * 16 + c;
                const int col = f * 32 + g * 8;
                kf[kj][f] = *reinterpret_cast<const short8*>(
                    &Ks[row * 64 + (col ^ ((row & 7) << 3))]);
            }

        f32x4 z = {0.f, 0.f, 0.f, 0.f};
        f32x4 s0 = __builtin_amdgcn_mfma_f32_16x16x32_bf16(qa0, kf[0][0], z, 0, 0, 0);
        s0 = __builtin_amdgcn_mfma_f32_16x16x32_bf16(qa1, kf[0][1], s0, 0, 0, 0);
        f32x4 s1 = __builtin_amdgcn_mfma_f32_16x16x32_bf16(qa0, kf[1][0], z, 0, 0, 0);
        s1 = __builtin_amdgcn_mfma_f32_16x16x32_bf16(qa1, kf[1][1], s1, 0, 0, 0);

#pragma unroll
        for (int r = 0; r < 4; ++r) {
            float p0 = exp2f(s0[r]);
            float p1 = exp2f(s1[r]);
            lsum[r] += p0 + p1;
            P[(4 * g + r) * LDP + c]      = f2bf(p0);
            P[(4 * g + r) * LDP + 16 + c] = f2bf(p1);
        }
        short8 pa = *reinterpret_cast<const short8*>(&P[c * LDP + g * 8]);

        short8 vf[4];
#pragma unroll
        for (int n = 0; n < 4; ++n)
            vf[n] = *reinterpret_cast<const short8*>(&Vs[(16 * n + c) * LDV + g * 8]);
#pragma unroll
        for (int n = 0; n < 4; ++n)
            acc[n] = __builtin_amdgcn_mfma_f32_16x16x32_bf16(pa, vf[n], acc[n], 0, 0, 0);
        __syncthreads();
    }

    // l reduction across the 16-lane c groups
#pragma unroll
    for (int off = 1; off < 16; off <<= 1)
#pragma unroll
        for (int r = 0; r < 4; ++r)
            lsum[r] += __shfl_xor(lsum[r], off, 64);

    // partial stores (f32, undivided)
#pragma unroll
    for (int r = 0; r < 4; ++r) {
        size_t row = ((size_t)(half * kBH + bh) * kT + qbase + 4 * g + r) * kDH;
#pragma unroll
        for (int n = 0; n < 4; ++n)
            pacc[row + 16 * n + c] = acc[n][r];
    }
    if (c == 0) {
#pragma unroll
        for (int r = 0; r < 4; ++r)
            pl[(size_t)(half * kBH + bh) * kT + qbase + 4 * g + r] = lsum[r];
    }
}

// ---------------------------------------------------------------------------
// Combine the two key-half partials: att = (a0+a1)/(l0+l1), bf16 (B,T,D).
// ---------------------------------------------------------------------------
__global__ __launch_bounds__(256)
void attn_combine(const float* __restrict__ pacc, const float* __restrict__ pl,
                  ushort_t* __restrict__ att_bf) {
    int flat = blockIdx.x * 256 + threadIdx.x;      // 2^20 threads
    int d4 = (flat & 15) * 4;
    int t  = (flat >> 4) & (kT - 1);
    int bh = flat >> 15;                            // 0..31
    int b = bh >> 4, h = bh & (kH - 1);

    size_t i0 = ((size_t)bh * kT + t) * kDH + d4;
    size_t i1 = ((size_t)(kBH + bh) * kT + t) * kDH + d4;
    float4 a0 = *reinterpret_cast<const float4*>(&pacc[i0]);
    float4 a1 = *reinterpret_cast<const float4*>(&pacc[i1]);
    float inv = 1.0f / (pl[(size_t)bh * kT + t] + pl[(size_t)(kBH + bh) * kT + t]);

    uint2 u;
    u.x = (unsigned int)f2bf((a0.x + a1.x) * inv) | ((unsigned int)f2bf((a0.y + a1.y) * inv) << 16);
    u.y = (unsigned int)f2bf((a0.z + a1.z) * inv) | ((unsigned int)f2bf((a0.w + a1.w) * inv) << 16);
    ushort_t* op = att_bf + ((size_t)(b * kT + t)) * kD + h * kDH + d4;
    *reinterpret_cast<uint2*>(op) = u;
}

// ---------------------------------------------------------------------------
extern "C" void kernel_launch(void* const* d_in, const int* in_sizes, int n_in,
                              void* d_out, int out_size, void* d_ws, size_t ws_size,
                              hipStream_t stream) {
    const float* x    = (const float*)d_in[0];
    const float* w_dk = (const float*)d_in[1];
    const float* b_dk = (const float*)d_in[2];
    const float* w_dv = (const float*)d_in[3];
    const float* b_dv = (const float*)d_in[4];
    const float* w_uk = (const float*)d_in[5];
    const float* b_uk = (const float*)d_in[6];
    const float* w_uv = (const float*)d_in[7];
    const float* b_uv = (const float*)d_in[8];
    const float* w_o  = (const float*)d_in[9];
    const float* b_o  = (const float*)d_in[10];
    float* out = (float*)d_out;

    char* w = (char*)d_ws;
    ushort_t* q_bf   = (ushort_t*)w;  w += (size_t)kM * kD * 2;    // q; reused as att
    ushort_t* k_bf   = (ushort_t*)w;  w += (size_t)kM * kD * 2;    // (B,H,T,DH)
    ushort_t* vt_bf  = (ushort_t*)w;  w += (size_t)kM * kD * 2;    // (B,H,DH,T)
    ushort_t* ckbf   = (ushort_t*)w;  w += (size_t)kM * kC * 2;
    ushort_t* cvbf   = (ushort_t*)w;  w += (size_t)kM * kC * 2;
    ushort_t* dkT    = (ushort_t*)w;  w += (size_t)kC * kD * 2;
    ushort_t* dvT    = (ushort_t*)w;  w += (size_t)kC * kD * 2;
    ushort_t* ukT    = (ushort_t*)w;  w += (size_t)kD * kC * 2;
    ushort_t* uvT    = (ushort_t*)w;  w += (size_t)kD * kC * 2;
    ushort_t* oT     = (ushort_t*)w;  w += (size_t)kD * kD * 2;
    float2*   tab    = (float2*)w;    w += (size_t)kT * 32 * 8;
    float*    pacc   = (float*)w;     w += (size_t)2 * kBH * kT * kDH * 4;  // 32 MB
    float*    pl     = (float*)w;     w += (size_t)2 * kBH * kT * 4;        // 0.5 MB

    dim3 blk(256);

    // 1. Weights -> bf16 (N,K) transposed; RoPE table (z=5).
    wtrans<<<dim3(32, 32, 6), blk, 0, stream>>>(w_dk, w_dv, w_uk, w_uv, w_o,
                                                dkT, dvT, ukT, uvT, oT, tab);

    // 2. Down-projection (A = x f32): c_k / c_v bf16 (M,N). 128x64 tiles.
    gemm64<true, 3><<<dim3(kC / 64, kM / 128, 2), blk, 0, stream>>>(
        x, x, dkT, b_dk, ckbf, dvT, b_dv, cvbf, kM, kC, kD);

    // 3. Up-projection: k_bf = rope(c_k@w_uk) split ; vt_bf = (c_v@w_uv)^T
    gemm_mfma<4, 2><<<dim3(kD / 128, kM / 128, 2), blk, 0, stream>>>(
        ckbf, cvbf, ukT, b_uk, k_bf, uvT, b_uv, vt_bf, tab, kM, kD, kC);

    // 4. q RoPE (separate kernel, r5 config).
    rope_split_q<<<(kB * kT * kH * 32) / 256, blk, 0, stream>>>(x, tab, q_bf);

    // 5. Attention, key-split x2 -> f32 partials. Grid 2048 = 8 blocks/CU.
    attn_mfma<<<dim3(kT / 64 * kBH * 2), blk, 0, stream>>>(q_bf, k_bf, vt_bf, pacc, pl);

    // 6. Combine halves -> att bf16 (B,T,D), into q_bf (dead after step 5).
    attn_combine<<<dim3(kBH * kT * kDH / (4 * 256)), blk, 0, stream>>>(pacc, pl, q_bf);

    // 7. Output projection: out = att @ w_o + b_o (f32). 128x64 tiles.
    gemm64<false, 0><<<dim3(kD / 64, kM / 128, 1), blk, 0, stream>>>(
        q_bf, q_bf, oT, b_o, out, oT, b_o, out, kM, kD, kD);
}

// Round 11
// 235.636 us; speedup vs baseline: 1.0875x; 1.0875x over previous
//
#include <hip/hip_runtime.h>
#include <hip/hip_bf16.h>
#include <math.h>

// Problem constants
constexpr int kB  = 2;
constexpr int kT  = 2048;
constexpr int kD  = 1024;
constexpr int kH  = 16;
constexpr int kDH = 64;     // per-head dim
constexpr int kC  = 128;    // compressed dim
constexpr int kM  = kB * kT;   // 4096 rows
constexpr int kBH = kB * kH;   // 32

#define LOG10000_OVER_32 0.28782313662425575f
#define QSCALE 0.1803368801111773f   // (1/8) * log2(e): softmax via exp2

typedef unsigned short ushort_t;
using short8 = __attribute__((ext_vector_type(8))) short;
using f32x4  = __attribute__((ext_vector_type(4))) float;

__device__ inline ushort_t f2bf(float f) {
    __hip_bfloat16 h = __float2bfloat16(f);
    return *reinterpret_cast<ushort_t*>(&h);
}

// 8 consecutive f32 -> short8 of bf16
__device__ inline short8 cvt8(const float* p) {
    float4 f0 = *reinterpret_cast<const float4*>(p);
    float4 f1 = *reinterpret_cast<const float4*>(p + 4);
    short8 v;
    v[0] = (short)f2bf(f0.x); v[1] = (short)f2bf(f0.y);
    v[2] = (short)f2bf(f0.z); v[3] = (short)f2bf(f0.w);
    v[4] = (short)f2bf(f1.x); v[5] = (short)f2bf(f1.y);
    v[6] = (short)f2bf(f1.z); v[7] = (short)f2bf(f1.w);
    return v;
}

// ---------------------------------------------------------------------------
// z=0..4: transpose-cast weight f32 (R,C) -> bf16 (C,R), 32x32 LDS tiles.
// z=5: build RoPE cos/sin table tab[t][i] (t<2048, i<32).
// ---------------------------------------------------------------------------
__global__ __launch_bounds__(256)
void wtrans(const float* __restrict__ w_dk, const float* __restrict__ w_dv,
            const float* __restrict__ w_uk, const float* __restrict__ w_uv,
            const float* __restrict__ w_o,
            ushort_t* __restrict__ dkT, ushort_t* __restrict__ dvT,
            ushort_t* __restrict__ ukT, ushort_t* __restrict__ uvT,
            ushort_t* __restrict__ oT, float2* __restrict__ tab) {
    if (blockIdx.z == 5) {
        int flat = blockIdx.y * 32 + blockIdx.x;
        if (flat >= kT / 8) return;
        int t = flat * 8 + (threadIdx.x >> 5);
        int i = threadIdx.x & 31;
        float inv_freq = expf(-(float)i * LOG10000_OVER_32);
        float s, c;
        sincosf((float)t * inv_freq, &s, &c);
        tab[t * 32 + i] = make_float2(c, s);
        return;
    }
    const float* src; ushort_t* dst; int R, C;
    switch (blockIdx.z) {
        case 0: src = w_dk; dst = dkT; R = kD; C = kC; break;
        case 1: src = w_dv; dst = dvT; R = kD; C = kC; break;
        case 2: src = w_uk; dst = ukT; R = kC; C = kD; break;
        case 3: src = w_uv; dst = uvT; R = kC; C = kD; break;
        default: src = w_o; dst = oT;  R = kD; C = kD; break;
    }
    int c0 = blockIdx.x * 32, r0 = blockIdx.y * 32;
    if (c0 >= C || r0 >= R) return;

    __shared__ float Tl[32][33];
    int tx = threadIdx.x & 31, ty = threadIdx.x >> 5;
#pragma unroll
    for (int i = 0; i < 4; ++i)
        Tl[ty + 8 * i][tx] = src[(size_t)(r0 + ty + 8 * i) * C + c0 + tx];
    __syncthreads();
#pragma unroll
    for (int i = 0; i < 4; ++i)
        dst[(size_t)(c0 + ty + 8 * i) * R + r0 + tx] = f2bf(Tl[tx][ty + 8 * i]);
}

// ---------------------------------------------------------------------------
// bf16 MFMA GEMM, 128x128 tile, BK=32, 4 waves (2x2), wave = 64x64 out.
// MODE: 2 = bf16 transposed V (B,H,DH,T); 4 = bf16 split + fused RoPE (k).
// Used for the up-projection only.
// ---------------------------------------------------------------------------
template<int MODE0, int MODE1>
__global__ __launch_bounds__(256)
void gemm_mfma(const ushort_t* __restrict__ A0_, const ushort_t* __restrict__ A1_,
               const ushort_t* __restrict__ Wt0, const float* __restrict__ bias0, void* __restrict__ C0,
               const ushort_t* __restrict__ Wt1, const float* __restrict__ bias1, void* __restrict__ C1,
               const float2* __restrict__ tab, int M, int N, int K) {
    constexpr int LDT = 40;
    __shared__ __align__(16) ushort_t As[128 * LDT];
    __shared__ __align__(16) ushort_t Bs[128 * LDT];

    const ushort_t* A    = blockIdx.z ? A1_ : A0_;
    const ushort_t* Wt   = blockIdx.z ? Wt1 : Wt0;
    const float*    bias = blockIdx.z ? bias1 : bias0;
    void*           Cc   = blockIdx.z ? C1 : C0;
    const int       mode = blockIdx.z ? MODE1 : MODE0;

    const int tid  = threadIdx.x;
    const int wave = tid >> 6, lane = tid & 63;
    const int g = lane >> 4, cl = lane & 15;
    const int m0 = blockIdx.y * 128, n0 = blockIdx.x * 128;
    const int wm = (wave >> 1) * 64, wn = (wave & 1) * 64;

    const int ar = tid >> 1;
    const int ac = (tid & 1) * 16;

    f32x4 acc[4][4] = {};

    for (int k0 = 0; k0 < K; k0 += 32) {
        {
            const ushort_t* Ab = A + (size_t)(m0 + ar) * K + k0 + ac;
            *reinterpret_cast<short8*>(&As[ar * LDT + ac])     = *reinterpret_cast<const short8*>(Ab);
            *reinterpret_cast<short8*>(&As[ar * LDT + ac + 8]) = *reinterpret_cast<const short8*>(Ab + 8);
            const ushort_t* Wb = Wt + (size_t)(n0 + ar) * K + k0 + ac;
            *reinterpret_cast<short8*>(&Bs[ar * LDT + ac])     = *reinterpret_cast<const short8*>(Wb);
            *reinterpret_cast<short8*>(&Bs[ar * LDT + ac + 8]) = *reinterpret_cast<const short8*>(Wb + 8);
        }
        __syncthreads();

        short8 a[4], b[4];
#pragma unroll
        for (int mi = 0; mi < 4; ++mi)
            a[mi] = *reinterpret_cast<const short8*>(&As[(wm + mi * 16 + cl) * LDT + g * 8]);
#pragma unroll
        for (int ni = 0; ni < 4; ++ni)
            b[ni] = *reinterpret_cast<const short8*>(&Bs[(wn + ni * 16 + cl) * LDT + g * 8]);
#pragma unroll
        for (int mi = 0; mi < 4; ++mi)
#pragma unroll
            for (int ni = 0; ni < 4; ++ni)
                acc[mi][ni] = __builtin_amdgcn_mfma_f32_16x16x32_bf16(a[mi], b[ni], acc[mi][ni], 0, 0, 0);
        __syncthreads();
    }

#pragma unroll
    for (int mi = 0; mi < 4; ++mi) {
        if (mode == 4) {
            const int h = (n0 + wn) >> 6;
#pragma unroll
            for (int r = 0; r < 4; ++r) {
                const int m = m0 + wm + mi * 16 + 4 * g + r;
                const int bb = m >> 11, t = m & (kT - 1);
                ushort_t* kp = (ushort_t*)Cc + (((size_t)bb * kH + h) * kT + t) * kDH;
#pragma unroll
                for (int pr = 0; pr < 2; ++pr) {
                    const int i = pr * 16 + cl;
                    float2 cs = tab[t * 32 + i];
                    float v1 = acc[mi][pr][r]     + bias[n0 + wn + pr * 16 + cl];
                    float v2 = acc[mi][pr + 2][r] + bias[n0 + wn + (pr + 2) * 16 + cl];
                    kp[i]      = f2bf(v1 * cs.x - v2 * cs.y);
                    kp[i + 32] = f2bf(v2 * cs.x + v1 * cs.y);
                }
            }
        } else {  // mode 2: bf16 V^T (B,H,DH,T)
#pragma unroll
            for (int ni = 0; ni < 4; ++ni) {
                const int mb = m0 + wm + mi * 16 + 4 * g;
                const int nn = n0 + wn + ni * 16 + cl;
                const float bv = bias[nn];
                const int h = nn >> 6, d = nn & (kDH - 1);
                const int bb = mb >> 11, t0 = mb & (kT - 1);
                uint2 u;
                u.x = (unsigned int)f2bf(acc[mi][ni][0] + bv) | ((unsigned int)f2bf(acc[mi][ni][1] + bv) << 16);
                u.y = (unsigned int)f2bf(acc[mi][ni][2] + bv) | ((unsigned int)f2bf(acc[mi][ni][3] + bv) << 16);
                ushort_t* vt = (ushort_t*)Cc;
                *reinterpret_cast<uint2*>(&vt[(((size_t)bb * kH + h) * kDH + d) * kT + t0]) = u;
            }
        }
    }
}

// ---------------------------------------------------------------------------
// bf16 MFMA GEMM, 128x64 tile, BK=32, 4 waves (2x2), wave = 64x32 out.
// AF32: A is f32 (cast in staging).  MODE: 0 = f32 (M,N); 3 = bf16 (M,N).
// ---------------------------------------------------------------------------
template<bool AF32, int MODE>
__global__ __launch_bounds__(256)
void gemm64(const void* __restrict__ A0_, const void* __restrict__ A1_,
            const ushort_t* __restrict__ Wt0, const float* __restrict__ bias0, void* __restrict__ C0,
            const ushort_t* __restrict__ Wt1, const float* __restrict__ bias1, void* __restrict__ C1,
            int M, int N, int K) {
    constexpr int LDT = 40;
    __shared__ __align__(16) ushort_t As[128 * LDT];
    __shared__ __align__(16) ushort_t Bs[64 * LDT];

    const void*     A    = blockIdx.z ? A1_ : A0_;
    const ushort_t* Wt   = blockIdx.z ? Wt1 : Wt0;
    const float*    bias = blockIdx.z ? bias1 : bias0;
    void*           Cc   = blockIdx.z ? C1 : C0;

    const int tid  = threadIdx.x;
    const int wave = tid >> 6, lane = tid & 63;
    const int g = lane >> 4, cl = lane & 15;
    const int m0 = blockIdx.y * 128, n0 = blockIdx.x * 64;
    const int wm = (wave >> 1) * 64, wn = (wave & 1) * 32;

    const int ar = tid >> 1, ac = (tid & 1) * 16;    // A: 128 rows x 2 chunks
    const int br = tid >> 2, bc = (tid & 3) * 8;     // B: 64 rows x 4 chunks

    f32x4 acc[4][2] = {};

    for (int k0 = 0; k0 < K; k0 += 32) {
        if constexpr (AF32) {
            const float* Af = (const float*)A + (size_t)(m0 + ar) * K + k0 + ac;
            *reinterpret_cast<short8*>(&As[ar * LDT + ac])     = cvt8(Af);
            *reinterpret_cast<short8*>(&As[ar * LDT + ac + 8]) = cvt8(Af + 8);
        } else {
            const ushort_t* Ab = (const ushort_t*)A + (size_t)(m0 + ar) * K + k0 + ac;
            *reinterpret_cast<short8*>(&As[ar * LDT + ac])     = *reinterpret_cast<const short8*>(Ab);
            *reinterpret_cast<short8*>(&As[ar * LDT + ac + 8]) = *reinterpret_cast<const short8*>(Ab + 8);
        }
        *reinterpret_cast<short8*>(&Bs[br * LDT + bc]) =
            *reinterpret_cast<const short8*>(Wt + (size_t)(n0 + br) * K + k0 + bc);
        __syncthreads();

        short8 a[4], b[2];
#pragma unroll
        for (int mi = 0; mi < 4; ++mi)
            a[mi] = *reinterpret_cast<const short8*>(&As[(wm + mi * 16 + cl) * LDT + g * 8]);
#pragma unroll
        for (int ni = 0; ni < 2; ++ni)
            b[ni] = *reinterpret_cast<const short8*>(&Bs[(wn + ni * 16 + cl) * LDT + g * 8]);
#pragma unroll
        for (int mi = 0; mi < 4; ++mi)
#pragma unroll
            for (int ni = 0; ni < 2; ++ni)
                acc[mi][ni] = __builtin_amdgcn_mfma_f32_16x16x32_bf16(a[mi], b[ni], acc[mi][ni], 0, 0, 0);
        __syncthreads();
    }

#pragma unroll
    for (int mi = 0; mi < 4; ++mi)
#pragma unroll
        for (int ni = 0; ni < 2; ++ni) {
            const int mb = m0 + wm + mi * 16 + 4 * g;
            const int nn = n0 + wn + ni * 16 + cl;
            const float bv = bias[nn];
            if constexpr (MODE == 0) {
#pragma unroll
                for (int r = 0; r < 4; ++r)
                    ((float*)Cc)[(size_t)(mb + r) * N + nn] = acc[mi][ni][r] + bv;
            } else {
#pragma unroll
                for (int r = 0; r < 4; ++r)
                    ((ushort_t*)Cc)[(size_t)(mb + r) * N + nn] = f2bf(acc[mi][ni][r] + bv);
            }
        }
}

// ---------------------------------------------------------------------------
// RoPE q (separate kernel — r5 config): x (B,T,D) f32 -> q_bf (B,H,T,DH)
// bf16 scaled by (1/8)*log2e.
// ---------------------------------------------------------------------------
__global__ __launch_bounds__(256)
void rope_split_q(const float* __restrict__ x, const float2* __restrict__ tab,
                  ushort_t* __restrict__ q_bf) {
    int idx = blockIdx.x * 256 + threadIdx.x;
    int i = idx & 31;
    int h = (idx >> 5) & (kH - 1);
    int t = (idx >> 9) & (kT - 1);
    int b = idx >> 20;

    const float* xp = x + ((size_t)(b * kT + t)) * kD + h * kDH;
    float x1 = xp[i];
    float x2 = xp[i + 32];
    float2 cs = tab[t * 32 + i];

    ushort_t* qp = q_bf + (((size_t)(b * kH + h)) * kT + t) * kDH;
    qp[i]      = f2bf((x1 * cs.x - x2 * cs.y) * QSCALE);
    qp[i + 32] = f2bf((x2 * cs.x + x1 * cs.y) * QSCALE);
}

// ---------------------------------------------------------------------------
// MFMA bf16 attention — EXACT r5 structure (best measured: 91 us).
// 4 waves x 16 q-rows; 32 keys/iter; grid 1024; single buffer, 2 barriers.
// K (32x64, LDK=72 pad) + V^T (64x32, LDV=40 pad) staged per block;
// P via wave-private LDS [16][32]. No-max exp2 softmax, deferred l-sum.
// ---------------------------------------------------------------------------
__global__ __launch_bounds__(256)
void attn_mfma(const ushort_t* __restrict__ q_bf, const ushort_t* __restrict__ k_bf,
               const ushort_t* __restrict__ vt_bf, ushort_t* __restrict__ att_bf) {
    constexpr int LDK = 72;   // 144B rows
    constexpr int LDV = 40;   // 80B rows
    const int blk  = blockIdx.x;
    const int bh   = (blk & 7) * 4 + ((blk >> 3) & 3);   // same bh -> same XCD
    const int qt   = blk >> 5;
    const int tid  = threadIdx.x;
    const int wave = tid >> 6;
    const int lane = tid & 63;
    const int g = lane >> 4, c = lane & 15;
    const int qbase = qt * 64 + wave * 16;

    __shared__ __align__(16) ushort_t Ks[32 * LDK];
    __shared__ __align__(16) ushort_t Vs[64 * LDV];
    __shared__ __align__(16) ushort_t P_lds[4][16][32];
    ushort_t (*P)[32] = P_lds[wave];

    // Q A-fragments (q pre-scaled by QSCALE)
    const ushort_t* qp = q_bf + ((size_t)bh * kT + qbase) * kDH;
    short8 qa0 = *reinterpret_cast<const short8*>(qp + (size_t)c * kDH + g * 8);
    short8 qa1 = *reinterpret_cast<const short8*>(qp + (size_t)c * kDH + g * 8 + 32);

    const ushort_t* kb = k_bf + (size_t)bh * kT * kDH;
    const ushort_t* vb = vt_bf + (size_t)bh * kDH * kT;

    // staging coords: K = 32 rows x 8 chunks, V = 64 rows x 4 chunks (16B each)
    const int kr_ = tid >> 3, kc_ = (tid & 7) * 8;
    const int vr_ = tid >> 2, vc_ = (tid & 3) * 8;

    f32x4 acc[4] = {};
    float lsum[4] = {0.f, 0.f, 0.f, 0.f};

    for (int kt = 0; kt < kT; kt += 32) {
        *reinterpret_cast<short8*>(&Ks[kr_ * LDK + kc_]) =
            *reinterpret_cast<const short8*>(&kb[(size_t)(kt + kr_) * kDH + kc_]);
        *reinterpret_cast<short8*>(&Vs[vr_ * LDV + vc_]) =
            *reinterpret_cast<const short8*>(&vb[(size_t)vr_ * kT + kt + vc_]);
        __syncthreads();

        short8 k00 = *reinterpret_cast<const short8*>(&Ks[c * LDK + g * 8]);
        short8 k01 = *reinterpret_cast<const short8*>(&Ks[c * LDK + 32 + g * 8]);
        short8 k10 = *reinterpret_cast<const short8*>(&Ks[(16 + c) * LDK + g * 8]);
        short8 k11 = *reinterpret_cast<const short8*>(&Ks[(16 + c) * LDK + 32 + g * 8]);

        f32x4 z = {0.f, 0.f, 0.f, 0.f};
        f32x4 s0 = __builtin_amdgcn_mfma_f32_16x16x32_bf16(qa0, k00, z, 0, 0, 0);
        s0 = __builtin_amdgcn_mfma_f32_16x16x32_bf16(qa1, k01, s0, 0, 0, 0);
        f32x4 s1 = __builtin_amdgcn_mfma_f32_16x16x32_bf16(qa0, k10, z, 0, 0, 0);
        s1 = __builtin_amdgcn_mfma_f32_16x16x32_bf16(qa1, k11, s1, 0, 0, 0);

        float p0[4], p1[4];
#pragma unroll
        for (int r = 0; r < 4; ++r) {
            p0[r] = exp2f(s0[r]);
            p1[r] = exp2f(s1[r]);
            lsum[r] += p0[r] + p1[r];
        }

        // P -> wave-private LDS (C layout) -> A fragment
#pragma unroll
        for (int r = 0; r < 4; ++r) {
            P[4 * g + r][c]      = f2bf(p0[r]);
            P[4 * g + r][16 + c] = f2bf(p1[r]);
        }
        short8 pa = *reinterpret_cast<const short8*>(&P[c][g * 8]);

        short8 vf[4];
#pragma unroll
        for (int n = 0; n < 4; ++n)
            vf[n] = *reinterpret_cast<const short8*>(&Vs[(16 * n + c) * LDV + g * 8]);
#pragma unroll
        for (int n = 0; n < 4; ++n)
            acc[n] = __builtin_amdgcn_mfma_f32_16x16x32_bf16(pa, vf[n], acc[n], 0, 0, 0);
        __syncthreads();
    }

    // deferred l reduction over the 16-lane row groups
#pragma unroll
    for (int off = 1; off < 16; off <<= 1)
#pragma unroll
        for (int r = 0; r < 4; ++r) lsum[r] += __shfl_xor(lsum[r], off, 64);

    const int b = bh >> 4, h = bh & (kH - 1);
#pragma unroll
    for (int r = 0; r < 4; ++r) {
        float inv_l = 1.0f / lsum[r];
        size_t row = (size_t)(b * kT + qbase + 4 * g + r) * kD + h * kDH;
#pragma unroll
        for (int n = 0; n < 4; ++n)
            att_bf[row + 16 * n + c] = f2bf(acc[n][r] * inv_l);
    }
}

// ---------------------------------------------------------------------------
extern "C" void kernel_launch(void* const* d_in, const int* in_sizes, int n_in,
                              void* d_out, int out_size, void* d_ws, size_t ws_size,
                              hipStream_t stream) {
    const float* x    = (const float*)d_in[0];
    const float* w_dk = (const float*)d_in[1];
    const float* b_dk = (const float*)d_in[2];
    const float* w_dv = (const float*)d_in[3];
    const float* b_dv = (const float*)d_in[4];
    const float* w_uk = (const float*)d_in[5];
    const float* b_uk = (const float*)d_in[6];
    const float* w_uv = (const float*)d_in[7];
    const float* b_uv = (const float*)d_in[8];
    const float* w_o  = (const float*)d_in[9];
    const float* b_o  = (const float*)d_in[10];
    float* out = (float*)d_out;

    char* w = (char*)d_ws;
    ushort_t* q_bf   = (ushort_t*)w;  w += (size_t)kM * kD * 2;
    ushort_t* k_bf   = (ushort_t*)w;  w += (size_t)kM * kD * 2;    // (B,H,T,DH)
    ushort_t* vt_bf  = (ushort_t*)w;  w += (size_t)kM * kD * 2;    // (B,H,DH,T)
    ushort_t* att_bf = (ushort_t*)w;  w += (size_t)kM * kD * 2;    // (B,T,D)
    ushort_t* ckbf   = (ushort_t*)w;  w += (size_t)kM * kC * 2;
    ushort_t* cvbf   = (ushort_t*)w;  w += (size_t)kM * kC * 2;
    ushort_t* dkT    = (ushort_t*)w;  w += (size_t)kC * kD * 2;
    ushort_t* dvT    = (ushort_t*)w;  w += (size_t)kC * kD * 2;
    ushort_t* ukT    = (ushort_t*)w;  w += (size_t)kD * kC * 2;
    ushort_t* uvT    = (ushort_t*)w;  w += (size_t)kD * kC * 2;
    ushort_t* oT     = (ushort_t*)w;  w += (size_t)kD * kD * 2;
    float2*   tab    = (float2*)w;    w += (size_t)kT * 32 * 8;

    dim3 blk(256);

    // 1. Weights -> bf16 (N,K) transposed; RoPE table (z=5).
    wtrans<<<dim3(32, 32, 6), blk, 0, stream>>>(w_dk, w_dv, w_uk, w_uv, w_o,
                                                dkT, dvT, ukT, uvT, oT, tab);

    // 2. Down-projection (A = x f32): c_k / c_v bf16 (M,N). 128x64 tiles.
    gemm64<true, 3><<<dim3(kC / 64, kM / 128, 2), blk, 0, stream>>>(
        x, x, dkT, b_dk, ckbf, dvT, b_dv, cvbf, kM, kC, kD);

    // 3. Up-projection: k_bf = rope(c_k@w_uk) split ; vt_bf = (c_v@w_uv)^T
    gemm_mfma<4, 2><<<dim3(kD / 128, kM / 128, 2), blk, 0, stream>>>(
        ckbf, cvbf, ukT, b_uk, k_bf, uvT, b_uv, vt_bf, tab, kM, kD, kC);

    // 4. q RoPE (separate kernel, r5 config).
    rope_split_q<<<(kB * kT * kH * 32) / 256, blk, 0, stream>>>(x, tab, q_bf);

    // 5. Attention (exact r5 kernel) -> att_bf (B,T,D) bf16.
    attn_mfma<<<dim3(kT / 64 * kBH), blk, 0, stream>>>(q_bf, k_bf, vt_bf, att_bf);

    // 6. Output projection: out = att_bf @ w_o + b_o (f32). 128x64 tiles.
    gemm64<false, 0><<<dim3(kD / 64, kM / 128, 1), blk, 0, stream>>>(
        att_bf, att_bf, oT, b_o, out, oT, b_o, out, kM, kD, kD);
}